// Round 9
// baseline (557.978 us; speedup 1.0000x reference)
//
#include <hip/hip_runtime.h>

typedef unsigned short u16;
using bf16x8 = __attribute__((ext_vector_type(8))) __bf16;
using f32x4  = __attribute__((ext_vector_type(4))) float;
using f32x16 = __attribute__((ext_vector_type(16))) float;
using u16x8  = __attribute__((ext_vector_type(8))) unsigned short;
using u16x4  = __attribute__((ext_vector_type(4))) unsigned short;

#define SEQ   2048
#define HID   1024
#define NHEAD 16
#define HD    64
#define BATCH 2
#define NTOK  4096   // BATCH*SEQ

__device__ __forceinline__ u16 f2bf(float f) {
  unsigned u = __builtin_bit_cast(unsigned, f);
  u += 0x7fffu + ((u >> 16) & 1u);
  return (u16)(u >> 16);
}

__device__ __forceinline__ void gld_lds16(const void* g, void* l) {
  __builtin_amdgcn_global_load_lds(
      (__attribute__((address_space(1))) void*)(__UINTPTR_TYPE__)g,
      (__attribute__((address_space(3))) void*)l, 16, 0, 0);
}

__device__ __forceinline__ unsigned cvtpk(float lo, float hi) {
  unsigned r;
  asm("v_cvt_pk_bf16_f32 %0, %1, %2" : "=v"(r) : "v"(lo), "v"(hi));
  return r;
}
__device__ __forceinline__ void pswap(unsigned &a, unsigned &b) {
  asm volatile("v_permlane32_swap_b32 %0, %1" : "+v"(a), "+v"(b));
}

// barrier that does NOT drain vmcnt (lane-private global prefetches stay in
// flight); lgkmcnt(0) makes this wave's ds_writes visible before the barrier.
__device__ __forceinline__ void lds_barrier() {
  __builtin_amdgcn_sched_barrier(0);
  asm volatile("s_waitcnt lgkmcnt(0)" ::: "memory");
  __builtin_amdgcn_s_barrier();
  __builtin_amdgcn_sched_barrier(0);
}

// ---------------- fp32 -> bf16 convert ----------------
__global__ __launch_bounds__(256) void cvt_kernel(const float* __restrict__ in,
                                                  u16* __restrict__ out) {
  int i = (blockIdx.x * 256 + threadIdx.x) * 4;
  float4 v = *reinterpret_cast<const float4*>(in + i);
  u16x4 o = { f2bf(v.x), f2bf(v.y), f2bf(v.z), f2bf(v.w) };
  *reinterpret_cast<u16x4*>(out + i) = o;
}

// ---------------- GEMM: C[M,N] = A[M,K] * B[N,K]^T ---------------- (unchanged)
template<bool BF16OUT>
__global__ __launch_bounds__(256) void gemm_bt(const u16* __restrict__ A,
                                               const u16* __restrict__ B,
                                               void* __restrict__ Cv,
                                               int M, int N, int K) {
  __shared__ u16 At[128 * 64];
  __shared__ u16 Bt[128 * 64];
  const int tid  = threadIdx.x;
  const int wave = tid >> 6;
  const int lane = tid & 63;
  const int g    = lane >> 4;
  const int r16  = lane & 15;
  const int wr   = wave >> 1;
  const int wc   = wave & 1;
  const int bm   = blockIdx.y;
  const int bn   = blockIdx.x;

  const u16* Ab = A + (size_t)bm * 128 * K;
  const u16* Bb = B + (size_t)bn * 128 * K;
  const int srow = lane >> 3;
  const int scol = (lane & 7) * 8;

  f32x4 acc[4][4] = {};

  for (int kt = 0; kt < K; kt += 64) {
#pragma unroll
    for (int c = 0; c < 4; ++c) {
      int seg = wave * 4 + c;
      gld_lds16(Ab + (size_t)(seg * 8 + srow) * K + kt + scol, &At[seg * 512]);
      gld_lds16(Bb + (size_t)(seg * 8 + srow) * K + kt + scol, &Bt[seg * 512]);
    }
    __syncthreads();
#pragma unroll
    for (int ko = 0; ko < 64; ko += 32) {
      bf16x8 af[4], bfr[4];
#pragma unroll
      for (int mi = 0; mi < 4; ++mi)
        af[mi] = *reinterpret_cast<const bf16x8*>(&At[(wr * 64 + mi * 16 + r16) * 64 + ko + g * 8]);
#pragma unroll
      for (int ni = 0; ni < 4; ++ni)
        bfr[ni] = *reinterpret_cast<const bf16x8*>(&Bt[(wc * 64 + ni * 16 + r16) * 64 + ko + g * 8]);
#pragma unroll
      for (int mi = 0; mi < 4; ++mi)
#pragma unroll
        for (int ni = 0; ni < 4; ++ni)
          acc[mi][ni] = __builtin_amdgcn_mfma_f32_16x16x32_bf16(af[mi], bfr[ni], acc[mi][ni], 0, 0, 0);
    }
    __syncthreads();
  }

#pragma unroll
  for (int mi = 0; mi < 4; ++mi)
#pragma unroll
    for (int ni = 0; ni < 4; ++ni) {
      int row0 = bm * 128 + wr * 64 + mi * 16 + g * 4;
      int col  = bn * 128 + wc * 64 + ni * 16 + r16;
#pragma unroll
      for (int r = 0; r < 4; ++r) {
        float v = acc[mi][ni][r];
        if (BF16OUT) ((u16*)Cv)[(size_t)(row0 + r) * N + col] = f2bf(v);
        else         ((float*)Cv)[(size_t)(row0 + r) * N + col] = v;
      }
    }
}

// ---------------- flash attention: swapped-QK^T 32x32, KV-split-2 ----------------
// 1024 blocks (XCD-grouped heads), 256 thr: wave w -> q-group (w&1), KV-half (w>>1).
// kvh=0 tiles 0,128,...; kvh=1 tiles 64,192,... Private (m,l,O); flash-merge at end
// through LDS (reusing Vt). 4096 waves = 4/SIMD. 1 barrier / 128 keys.
__global__ __launch_bounds__(256, 4) void attn_kernel(const u16* __restrict__ qkv,
                                                      const float* __restrict__ mask,
                                                      u16* __restrict__ AO) {
  __shared__ u16 Vt[2][2][64 * 64];   // [phase][kvh][d][key] swizzled

  const int tid  = threadIdx.x;
  const int w    = tid >> 6;
  const int lane = tid & 63;
  const int q31  = lane & 31;
  const int hi   = lane >> 5;
  const int qg   = w & 1;
  const int kvh  = w >> 1;

  const int n  = blockIdx.x;           // 0..1023
  const int x  = n & 7;
  const int s_ = n >> 3;               // 0..127
  const int h  = s_ & 15;
  const int t_ = ((s_ >> 4) << 3) + x; // 0..63
  const int b  = t_ >> 5;
  const int qt = t_ & 31;              // 64-row q tiles

  const size_t tokbase = (size_t)b * SEQ;
  const int q_lane = qt * 64 + qg * 32 + q31;

  bf16x8 qf[4];
  {
    const u16* qb = qkv + ((tokbase + q_lane) * 3 + 0) * HID + h * HD + 8 * hi;
#pragma unroll
    for (int s = 0; s < 4; ++s)
      qf[s] = *reinterpret_cast<const bf16x8*>(qb + 16 * s);
  }
  const float* mrowp = mask + ((size_t)b * SEQ + q_lane) * SEQ;

  f32x16 oa0 = {}, oa1 = {};
  float mold = -3.0e38f, lsum = 0.f;

  const int vkey = tid >> 2;
  const int vd3  = tid & 3;

#define STAGE_V(ph, half, va, vb)                                              \
  {                                                                            \
    _Pragma("unroll")                                                          \
    for (int j = 0; j < 16; ++j) {                                             \
      u16 val = (j < 8) ? (u16)(va)[j] : (u16)(vb)[j - 8];                     \
      int row = vd3 * 16 + j;                                                  \
      int sV  = (vd3 + (j & 7)) & 7;                                           \
      Vt[ph][half][row * 64 + (((vkey >> 3) ^ sV) << 3) + (vkey & 7)] = val;   \
    }                                                                          \
  }

  // ---- prologue: K frags + mask for own tile (kb = 64*kvh); V pair for phase 0 ----
  bf16x8 kf[2][4];
#pragma unroll
  for (int t = 0; t < 2; ++t) {
    const u16* kb_ = qkv + ((tokbase + 64 * kvh + 32 * t + q31) * 3 + 1) * HID + h * HD + 8 * hi;
#pragma unroll
    for (int s = 0; s < 4; ++s)
      kf[t][s] = *reinterpret_cast<const bf16x8*>(kb_ + 16 * s);
  }
  float4 mreg[8];
#pragma unroll
  for (int t = 0; t < 2; ++t)
#pragma unroll
    for (int a = 0; a < 4; ++a)
      mreg[t * 4 + a] = *reinterpret_cast<const float4*>(
          mrowp + 64 * kvh + 32 * t + 8 * a + 4 * hi);
  u16x8 va0, va1, vb0, vb1;
  {
    const u16* vpa = qkv + ((tokbase + 0 + vkey) * 3 + 2) * HID + h * HD + vd3 * 16;
    va0 = *reinterpret_cast<const u16x8*>(vpa);
    va1 = *reinterpret_cast<const u16x8*>(vpa + 8);
    const u16* vpb = qkv + ((tokbase + 64 + vkey) * 3 + 2) * HID + h * HD + vd3 * 16;
    vb0 = *reinterpret_cast<const u16x8*>(vpb);
    vb1 = *reinterpret_cast<const u16x8*>(vpb + 8);
  }
  STAGE_V(0, 0, va0, va1);
  STAGE_V(0, 1, vb0, vb1);
  lds_barrier();   // phase-0 V pair visible

#pragma unroll 1
  for (int p = 0; p < 16; ++p) {
    const int cur  = p & 1;
    const int nxt  = cur ^ 1;
    const bool more = p < 15;
    const int kb   = 128 * p + 64 * kvh;   // this wave's 64-key tile

    // ---- S^T = K * Q^T ----
    f32x16 sa0 = {}, sa1 = {};
#pragma unroll
    for (int s = 0; s < 4; ++s)
      sa0 = __builtin_amdgcn_mfma_f32_32x32x16_bf16(kf[0][s], qf[s], sa0, 0, 0, 0);
#pragma unroll
    for (int s = 0; s < 4; ++s)
      sa1 = __builtin_amdgcn_mfma_f32_32x32x16_bf16(kf[1][s], qf[s], sa1, 0, 0, 0);

    // ---- issue next phase's K frags (own tile) + V pair (regs reused in place) ----
    if (more) {
#pragma unroll
      for (int t = 0; t < 2; ++t) {
        const u16* kb_ = qkv + ((tokbase + kb + 128 + 32 * t + q31) * 3 + 1) * HID + h * HD + 8 * hi;
#pragma unroll
        for (int s = 0; s < 4; ++s)
          kf[t][s] = *reinterpret_cast<const bf16x8*>(kb_ + 16 * s);
      }
      const u16* vpa = qkv + ((tokbase + 128 * (p + 1) + vkey) * 3 + 2) * HID + h * HD + vd3 * 16;
      va0 = *reinterpret_cast<const u16x8*>(vpa);
      va1 = *reinterpret_cast<const u16x8*>(vpa + 8);
      const u16* vpb = qkv + ((tokbase + 128 * (p + 1) + 64 + vkey) * 3 + 2) * HID + h * HD + vd3 * 16;
      vb0 = *reinterpret_cast<const u16x8*>(vpb);
      vb1 = *reinterpret_cast<const u16x8*>(vpb + 8);
    }

    // ---- scale + mask from prefetched regs ----
#pragma unroll
    for (int t = 0; t < 2; ++t) {
      f32x16& sa = t ? sa1 : sa0;
#pragma unroll
      for (int r = 0; r < 16; ++r)
        sa[r] = sa[r] * 0.125f +
                reinterpret_cast<const float*>(&mreg[t * 4 + (r >> 2)])[r & 3];
    }
    if (more) {
#pragma unroll
      for (int t = 0; t < 2; ++t)
#pragma unroll
        for (int a = 0; a < 4; ++a)
          mreg[t * 4 + a] = *reinterpret_cast<const float4*>(
              mrowp + kb + 128 + 32 * t + 8 * a + 4 * hi);
    }

    // ---- lane-local online softmax ----
    float mx = -3.0e38f;
#pragma unroll
    for (int r = 0; r < 16; ++r) mx = fmaxf(mx, sa0[r]);
#pragma unroll
    for (int r = 0; r < 16; ++r) mx = fmaxf(mx, sa1[r]);
    mx = fmaxf(mx, __shfl_xor(mx, 32));
    float mnew  = fmaxf(mold, mx);
    float alpha = __expf(mold - mnew);
    mold = mnew;
#pragma unroll
    for (int r = 0; r < 16; ++r) { oa0[r] *= alpha; oa1[r] *= alpha; }
    float ps = 0.f;
#pragma unroll
    for (int r = 0; r < 16; ++r) { float p_ = __expf(sa0[r] - mnew); sa0[r] = p_; ps += p_; }
#pragma unroll
    for (int r = 0; r < 16; ++r) { float p_ = __expf(sa1[r] - mnew); sa1[r] = p_; ps += p_; }
    ps += __shfl_xor(ps, 32);
    lsum = lsum * alpha + ps;

    // ---- PV on Vt[cur][kvh] ----
#pragma unroll
    for (int c = 0; c < 4; ++c) {
      const int cl = c & 1;
      const f32x16& sa = (c >> 1) ? sa1 : sa0;
      unsigned X0 = cvtpk(sa[8 * cl + 0], sa[8 * cl + 1]);
      unsigned X1 = cvtpk(sa[8 * cl + 2], sa[8 * cl + 3]);
      unsigned X2 = cvtpk(sa[8 * cl + 4], sa[8 * cl + 5]);
      unsigned X3 = cvtpk(sa[8 * cl + 6], sa[8 * cl + 7]);
      pswap(X0, X2);
      pswap(X1, X3);
      union { unsigned u[4]; bf16x8 v; } pb;
      pb.u[0] = X0; pb.u[1] = X1; pb.u[2] = X2; pb.u[3] = X3;
#pragma unroll
      for (int dt = 0; dt < 2; ++dt) {
        int row  = dt * 32 + q31;
        int srow = ((row >> 4) + (row & 7)) & 7;
        bf16x8 va = *reinterpret_cast<const bf16x8*>(
            &Vt[cur][kvh][row * 64 + (((2 * c + hi) ^ srow) << 3)]);
        f32x16& oa = dt ? oa1 : oa0;
        oa = __builtin_amdgcn_mfma_f32_32x32x16_bf16(va, pb.v, oa, 0, 0, 0);
      }
    }

    // ---- stage next phase's V pair ----
    if (more) {
      STAGE_V(nxt, 0, va0, va1);
      STAGE_V(nxt, 1, vb0, vb1);
    }
    lds_barrier();
  }

  // ---- flash-merge the two KV halves (reuse Vt as f32 scratch) ----
  // per q-group: oa [32 rows][64 lanes] = 2048 f32, then m (64), l (64)
  float* mb   = reinterpret_cast<float*>(&Vt[0][0][0]);
  float* base = mb + qg * 2176;
  if (kvh == 1) {
#pragma unroll
    for (int r = 0; r < 16; ++r) {
      base[r * 64 + lane]        = oa0[r];
      base[(16 + r) * 64 + lane] = oa1[r];
    }
    base[2048 + lane] = mold;
    base[2112 + lane] = lsum;
  }
  lds_barrier();
  if (kvh == 0) {
    float mB = base[2048 + lane];
    float lB = base[2112 + lane];
    float mstar = fmaxf(mold, mB);
    float fA = __expf(mold - mstar);
    float fB = __expf(mB - mstar);
    float linv = 1.0f / (lsum * fA + lB * fB);
    u16* ob = AO + (tokbase + q_lane) * HID + h * HD;
#pragma unroll
    for (int dt = 0; dt < 2; ++dt) {
      const f32x16& oa = dt ? oa1 : oa0;
#pragma unroll
      for (int a = 0; a < 4; ++a) {
        u16x4 pk_;
#pragma unroll
        for (int i = 0; i < 4; ++i) {
          float vB = base[(dt * 16 + 4 * a + i) * 64 + lane];
          pk_[i] = f2bf((oa[4 * a + i] * fA + vB * fB) * linv);
        }
        *reinterpret_cast<u16x4*>(ob + dt * 32 + 8 * a + 4 * hi) = pk_;
      }
    }
  }
#undef STAGE_V
}

// ---------------- launcher ----------------
extern "C" void kernel_launch(void* const* d_in, const int* in_sizes, int n_in,
                              void* d_out, int out_size, void* d_ws, size_t ws_size,
                              hipStream_t stream) {
  (void)in_sizes; (void)n_in; (void)out_size; (void)ws_size;
  const float* hs   = (const float*)d_in[0];
  const float* mask = (const float*)d_in[1];
  const float* wqkv = (const float*)d_in[2];
  const float* wo   = (const float*)d_in[3];
  float* out = (float*)d_out;

  char* ws   = (char*)d_ws;
  u16* Xb    = (u16*)(ws);                        // 4096x1024  (8 MiB)
  u16* Wqkvb = (u16*)(ws + 8u  * 1024 * 1024);    // 3072x1024  (6 MiB)
  u16* Wob   = (u16*)(ws + 14u * 1024 * 1024);    // 1024x1024  (2 MiB)
  u16* QKVb  = (u16*)(ws + 16u * 1024 * 1024);    // 4096x3072  (24 MiB)
  u16* AOb   = (u16*)(ws + 40u * 1024 * 1024);    // 4096x1024  (8 MiB)

  cvt_kernel<<<4096, 256, 0, stream>>>(hs,   Xb);
  cvt_kernel<<<3072, 256, 0, stream>>>(wqkv, Wqkvb);
  cvt_kernel<<<1024, 256, 0, stream>>>(wo,   Wob);

  gemm_bt<true ><<<dim3(3072 / 128, 4096 / 128), 256, 0, stream>>>(Xb,  Wqkvb, QKVb, NTOK, 3072, HID);
  attn_kernel   <<<1024, 256, 0, stream>>>(QKVb, mask, AOb);
  gemm_bt<false><<<dim3(1024 / 128, 4096 / 128), 256, 0, stream>>>(AOb, Wob,  out,  NTOK, 1024, HID);
}

// Round 10
// 282.583 us; speedup vs baseline: 1.9746x; 1.9746x over previous
//
#include <hip/hip_runtime.h>

typedef unsigned short u16;
using bf16x8 = __attribute__((ext_vector_type(8))) __bf16;
using f32x4  = __attribute__((ext_vector_type(4))) float;
using f32x16 = __attribute__((ext_vector_type(16))) float;
using u16x8  = __attribute__((ext_vector_type(8))) unsigned short;
using u16x4  = __attribute__((ext_vector_type(4))) unsigned short;

#define SEQ   2048
#define HID   1024
#define NHEAD 16
#define HD    64
#define BATCH 2
#define NTOK  4096   // BATCH*SEQ

__device__ __forceinline__ u16 f2bf(float f) {
  unsigned u = __builtin_bit_cast(unsigned, f);
  u += 0x7fffu + ((u >> 16) & 1u);
  return (u16)(u >> 16);
}

__device__ __forceinline__ void gld_lds16(const void* g, void* l) {
  __builtin_amdgcn_global_load_lds(
      (__attribute__((address_space(1))) void*)(__UINTPTR_TYPE__)g,
      (__attribute__((address_space(3))) void*)l, 16, 0, 0);
}

__device__ __forceinline__ unsigned cvtpk(float lo, float hi) {
  unsigned r;
  asm("v_cvt_pk_bf16_f32 %0, %1, %2" : "=v"(r) : "v"(lo), "v"(hi));
  return r;
}
__device__ __forceinline__ void pswap(unsigned &a, unsigned &b) {
  asm volatile("v_permlane32_swap_b32 %0, %1" : "+v"(a), "+v"(b));
}

// barrier that does NOT drain vmcnt (lane-private global prefetches stay in
// flight); lgkmcnt(0) makes this wave's ds_writes visible before the barrier.
__device__ __forceinline__ void lds_barrier() {
  __builtin_amdgcn_sched_barrier(0);
  asm volatile("s_waitcnt lgkmcnt(0)" ::: "memory");
  __builtin_amdgcn_s_barrier();
  __builtin_amdgcn_sched_barrier(0);
}

// ---------------- fp32 -> bf16 convert ----------------
__global__ __launch_bounds__(256) void cvt_kernel(const float* __restrict__ in,
                                                  u16* __restrict__ out) {
  int i = (blockIdx.x * 256 + threadIdx.x) * 4;
  float4 v = *reinterpret_cast<const float4*>(in + i);
  u16x4 o = { f2bf(v.x), f2bf(v.y), f2bf(v.z), f2bf(v.w) };
  *reinterpret_cast<u16x4*>(out + i) = o;
}

// ---------------- GEMM: C[M,N] = A[M,K] * B[N,K]^T ---------------- (unchanged)
template<bool BF16OUT>
__global__ __launch_bounds__(256) void gemm_bt(const u16* __restrict__ A,
                                               const u16* __restrict__ B,
                                               void* __restrict__ Cv,
                                               int M, int N, int K) {
  __shared__ u16 At[128 * 64];
  __shared__ u16 Bt[128 * 64];
  const int tid  = threadIdx.x;
  const int wave = tid >> 6;
  const int lane = tid & 63;
  const int g    = lane >> 4;
  const int r16  = lane & 15;
  const int wr   = wave >> 1;
  const int wc   = wave & 1;
  const int bm   = blockIdx.y;
  const int bn   = blockIdx.x;

  const u16* Ab = A + (size_t)bm * 128 * K;
  const u16* Bb = B + (size_t)bn * 128 * K;
  const int srow = lane >> 3;
  const int scol = (lane & 7) * 8;

  f32x4 acc[4][4] = {};

  for (int kt = 0; kt < K; kt += 64) {
#pragma unroll
    for (int c = 0; c < 4; ++c) {
      int seg = wave * 4 + c;
      gld_lds16(Ab + (size_t)(seg * 8 + srow) * K + kt + scol, &At[seg * 512]);
      gld_lds16(Bb + (size_t)(seg * 8 + srow) * K + kt + scol, &Bt[seg * 512]);
    }
    __syncthreads();
#pragma unroll
    for (int ko = 0; ko < 64; ko += 32) {
      bf16x8 af[4], bfr[4];
#pragma unroll
      for (int mi = 0; mi < 4; ++mi)
        af[mi] = *reinterpret_cast<const bf16x8*>(&At[(wr * 64 + mi * 16 + r16) * 64 + ko + g * 8]);
#pragma unroll
      for (int ni = 0; ni < 4; ++ni)
        bfr[ni] = *reinterpret_cast<const bf16x8*>(&Bt[(wc * 64 + ni * 16 + r16) * 64 + ko + g * 8]);
#pragma unroll
      for (int mi = 0; mi < 4; ++mi)
#pragma unroll
        for (int ni = 0; ni < 4; ++ni)
          acc[mi][ni] = __builtin_amdgcn_mfma_f32_16x16x32_bf16(af[mi], bfr[ni], acc[mi][ni], 0, 0, 0);
    }
    __syncthreads();
  }

#pragma unroll
  for (int mi = 0; mi < 4; ++mi)
#pragma unroll
    for (int ni = 0; ni < 4; ++ni) {
      int row0 = bm * 128 + wr * 64 + mi * 16 + g * 4;
      int col  = bn * 128 + wc * 64 + ni * 16 + r16;
#pragma unroll
      for (int r = 0; r < 4; ++r) {
        float v = acc[mi][ni][r];
        if (BF16OUT) ((u16*)Cv)[(size_t)(row0 + r) * N + col] = f2bf(v);
        else         ((float*)Cv)[(size_t)(row0 + r) * N + col] = v;
      }
    }
}

// ---------------- flash attention: swapped-QK^T 32x32, KV-split-2 ----------------
// 512 blocks x 512 thr (8 waves): qg = w&3 (4 x 32 q-rows = 128 q/block),
// kvh = w>>2 (KV halves of each 64-key phase). 32 phases x 64 keys.
// Per wave per phase: one 32-key tile: 4 QK mfma + 16-elem softmax + 4 PV mfma.
// Register-engineered <=128 VGPR for 4 waves/SIMD. Flash-merge at end via LDS.
// Block->XCD grouping: bh = n&31 -> KV L2 reuse (4 bh pairs per XCD = 2MB).
__global__ __launch_bounds__(512, 4) void attn_kernel(const u16* __restrict__ qkv,
                                                      const float* __restrict__ mask,
                                                      u16* __restrict__ AO) {
  __shared__ __align__(16) char smem[34816];   // Vt 16KB (loop) / merge 34KB (end)
  u16*   Vt = reinterpret_cast<u16*>(smem);    // [phase][half][2048] swizzled V^T
  float* mg = reinterpret_cast<float*>(smem);

  const int tid  = threadIdx.x;
  const int w    = tid >> 6;
  const int lane = tid & 63;
  const int q31  = lane & 31;
  const int hi   = lane >> 5;
  const int qg   = w & 3;
  const int kvh  = w >> 2;

  const int n  = blockIdx.x;     // 0..511 ; XCD = n&7 = bh&7 (KV L2 reuse)
  const int bh = n & 31;
  const int qt = n >> 5;         // 0..15 (128-row q tiles)
  const int b  = bh >> 4;
  const int h  = bh & 15;

  const size_t tokbase = (size_t)b * SEQ;
  const int q_lane = qt * 128 + qg * 32 + q31;

  // Q fragments (B-operand): col=q31, d = 16s + 8hi + j
  bf16x8 qf[4];
  {
    const u16* qb = qkv + ((tokbase + q_lane) * 3 + 0) * HID + h * HD + 8 * hi;
#pragma unroll
    for (int s = 0; s < 4; ++s)
      qf[s] = *reinterpret_cast<const bf16x8*>(qb + 16 * s);
  }
  const float* mrowp = mask + ((size_t)b * SEQ + q_lane) * SEQ;

  f32x16 oa0 = {}, oa1 = {};
  float mold = -3.0e38f, lsum = 0.f;

  // V staging map: thread -> (key, d-octet)
  const int keyIdx = tid >> 3;         // 0..63 within phase
  const int d0     = (tid & 7) * 8;
  const int k31s   = keyIdx & 31;
  const int halfs  = keyIdx >> 5;

  // swizzle: s(d) = ((d>>2)+d)&3 ; chunk' = (lin_chunk ^ s) & 3
#define VT_W(ph, d_, val)                                                       \
  Vt[((ph) * 2 + halfs) * 2048 + (d_) * 32 +                                    \
     ((((k31s >> 3) ^ (((d_) >> 2) + (d_))) & 3) << 3) + (k31s & 7)] = (val)

  // ---- prologue: kf/mreg (own tile, phase 0), v (phase 0), stage Vt[0] ----
  bf16x8 kf[4];
  {
    const u16* kb_ = qkv + ((tokbase + 32 * kvh + q31) * 3 + 1) * HID + h * HD + 8 * hi;
#pragma unroll
    for (int s = 0; s < 4; ++s)
      kf[s] = *reinterpret_cast<const bf16x8*>(kb_ + 16 * s);
  }
  float4 mreg[4];
#pragma unroll
  for (int a = 0; a < 4; ++a)
    mreg[a] = *reinterpret_cast<const float4*>(mrowp + 32 * kvh + 8 * a + 4 * hi);
  u16x8 vreg;
  vreg = *reinterpret_cast<const u16x8*>(
      qkv + ((tokbase + keyIdx) * 3 + 2) * HID + h * HD + d0);
#pragma unroll
  for (int j = 0; j < 8; ++j) VT_W(0, d0 + j, (u16)vreg[j]);
  lds_barrier();

#pragma unroll 1
  for (int p = 0; p < 32; ++p) {
    const int cur  = p & 1;
    const int nxt  = cur ^ 1;
    const bool more = p < 31;
    const int kb   = 64 * p + 32 * kvh;   // this wave's 32-key tile

    // ---- S^T = K * Q^T (one 32x32 tile, 4 k-slices) ----
    f32x16 sa = {};
#pragma unroll
    for (int s = 0; s < 4; ++s)
      sa = __builtin_amdgcn_mfma_f32_32x32x16_bf16(kf[s], qf[s], sa, 0, 0, 0);

    // ---- issue next phase's K frags + V regs (reuse regs in place) ----
    if (more) {
      const u16* kb_ = qkv + ((tokbase + kb + 64 + q31) * 3 + 1) * HID + h * HD + 8 * hi;
#pragma unroll
      for (int s = 0; s < 4; ++s)
        kf[s] = *reinterpret_cast<const bf16x8*>(kb_ + 16 * s);
      vreg = *reinterpret_cast<const u16x8*>(
          qkv + ((tokbase + 64 * (p + 1) + keyIdx) * 3 + 2) * HID + h * HD + d0);
    }

    // ---- scale + mask from prefetched regs; then prefetch next mask ----
#pragma unroll
    for (int r = 0; r < 16; ++r)
      sa[r] = sa[r] * 0.125f +
              reinterpret_cast<const float*>(&mreg[r >> 2])[r & 3];
    if (more) {
#pragma unroll
      for (int a = 0; a < 4; ++a)
        mreg[a] = *reinterpret_cast<const float4*>(mrowp + kb + 64 + 8 * a + 4 * hi);
    }

    // ---- lane-local online softmax (16 S-values) ----
    float mx = sa[0];
#pragma unroll
    for (int r = 1; r < 16; ++r) mx = fmaxf(mx, sa[r]);
    mx = fmaxf(mx, __shfl_xor(mx, 32));
    float mnew  = fmaxf(mold, mx);
    float alpha = __expf(mold - mnew);
    mold = mnew;
#pragma unroll
    for (int r = 0; r < 16; ++r) { oa0[r] *= alpha; oa1[r] *= alpha; }
    float ps = 0.f;
#pragma unroll
    for (int r = 0; r < 16; ++r) { float p_ = __expf(sa[r] - mnew); sa[r] = p_; ps += p_; }
    ps += __shfl_xor(ps, 32);
    lsum = lsum * alpha + ps;

    // ---- PV on Vt[cur][kvh]: 2 chunks of 16 keys ----
#pragma unroll
    for (int c = 0; c < 2; ++c) {
      unsigned X0 = cvtpk(sa[8 * c + 0], sa[8 * c + 1]);
      unsigned X1 = cvtpk(sa[8 * c + 2], sa[8 * c + 3]);
      unsigned X2 = cvtpk(sa[8 * c + 4], sa[8 * c + 5]);
      unsigned X3 = cvtpk(sa[8 * c + 6], sa[8 * c + 7]);
      pswap(X0, X2);
      pswap(X1, X3);
      union { unsigned u[4]; bf16x8 v; } pb;
      pb.u[0] = X0; pb.u[1] = X1; pb.u[2] = X2; pb.u[3] = X3;
#pragma unroll
      for (int dt = 0; dt < 2; ++dt) {
        int row = dt * 32 + q31;
        int chk = (((2 * c + hi) ^ ((row >> 2) + row)) & 3);
        bf16x8 va = *reinterpret_cast<const bf16x8*>(
            &Vt[(cur * 2 + kvh) * 2048 + row * 32 + (chk << 3)]);
        f32x16& oa = dt ? oa1 : oa0;
        oa = __builtin_amdgcn_mfma_f32_32x32x16_bf16(va, pb.v, oa, 0, 0, 0);
      }
    }

    // ---- stage next phase's V (vreg landed during compute) ----
    if (more) {
#pragma unroll
      for (int j = 0; j < 8; ++j) VT_W(nxt, d0 + j, (u16)vreg[j]);
    }
    lds_barrier();
  }

  // ---- flash-merge the two KV halves (LDS scratch over Vt) ----
  float* base = mg + qg * 2176;
  if (kvh == 1) {
#pragma unroll
    for (int r = 0; r < 16; ++r) {
      base[r * 64 + lane]        = oa0[r];
      base[(16 + r) * 64 + lane] = oa1[r];
    }
    base[2048 + lane] = mold;
    base[2112 + lane] = lsum;
  }
  lds_barrier();
  if (kvh == 0) {
    float mB = base[2048 + lane];
    float lB = base[2112 + lane];
    float mstar = fmaxf(mold, mB);
    float fA = __expf(mold - mstar);
    float fB = __expf(mB - mstar);
    float linv = 1.0f / (lsum * fA + lB * fB);
    u16* ob = AO + (tokbase + q_lane) * HID + h * HD;
#pragma unroll
    for (int dt = 0; dt < 2; ++dt) {
      const f32x16& oa = dt ? oa1 : oa0;
#pragma unroll
      for (int a = 0; a < 4; ++a) {
        u16x4 pk_;
#pragma unroll
        for (int i = 0; i < 4; ++i) {
          float vB = base[(dt * 16 + 4 * a + i) * 64 + lane];
          pk_[i] = f2bf((oa[4 * a + i] * fA + vB * fB) * linv);
        }
        *reinterpret_cast<u16x4*>(ob + dt * 32 + 8 * a + 4 * hi) = pk_;
      }
    }
  }
#undef VT_W
}

// ---------------- launcher ----------------
extern "C" void kernel_launch(void* const* d_in, const int* in_sizes, int n_in,
                              void* d_out, int out_size, void* d_ws, size_t ws_size,
                              hipStream_t stream) {
  (void)in_sizes; (void)n_in; (void)out_size; (void)ws_size;
  const float* hs   = (const float*)d_in[0];
  const float* mask = (const float*)d_in[1];
  const float* wqkv = (const float*)d_in[2];
  const float* wo   = (const float*)d_in[3];
  float* out = (float*)d_out;

  char* ws   = (char*)d_ws;
  u16* Xb    = (u16*)(ws);                        // 4096x1024  (8 MiB)
  u16* Wqkvb = (u16*)(ws + 8u  * 1024 * 1024);    // 3072x1024  (6 MiB)
  u16* Wob   = (u16*)(ws + 14u * 1024 * 1024);    // 1024x1024  (2 MiB)
  u16* QKVb  = (u16*)(ws + 16u * 1024 * 1024);    // 4096x3072  (24 MiB)
  u16* AOb   = (u16*)(ws + 40u * 1024 * 1024);    // 4096x1024  (8 MiB)

  cvt_kernel<<<4096, 256, 0, stream>>>(hs,   Xb);
  cvt_kernel<<<3072, 256, 0, stream>>>(wqkv, Wqkvb);
  cvt_kernel<<<1024, 256, 0, stream>>>(wo,   Wob);

  gemm_bt<true ><<<dim3(3072 / 128, 4096 / 128), 256, 0, stream>>>(Xb,  Wqkvb, QKVb, NTOK, 3072, HID);
  attn_kernel   <<<512, 512, 0, stream>>>(QKVb, mask, AOb);
  gemm_bt<false><<<dim3(1024 / 128, 4096 / 128), 256, 0, stream>>>(AOb, Wob,  out,  NTOK, 1024, HID);
}

// Round 11
// 198.340 us; speedup vs baseline: 2.8132x; 1.4247x over previous
//
#include <hip/hip_runtime.h>

typedef unsigned short u16;
using bf16x8 = __attribute__((ext_vector_type(8))) __bf16;
using f32x4  = __attribute__((ext_vector_type(4))) float;
using u16x8  = __attribute__((ext_vector_type(8))) unsigned short;
using u16x4  = __attribute__((ext_vector_type(4))) unsigned short;

#define SEQ   2048
#define HID   1024
#define NHEAD 16
#define HD    64
#define BATCH 2
#define NTOK  4096   // BATCH*SEQ

__device__ __forceinline__ u16 f2bf(float f) {
  unsigned u = __builtin_bit_cast(unsigned, f);
  u += 0x7fffu + ((u >> 16) & 1u);
  return (u16)(u >> 16);
}

__device__ __forceinline__ void gld_lds16(const void* g, void* l) {
  __builtin_amdgcn_global_load_lds(
      (__attribute__((address_space(1))) void*)(__UINTPTR_TYPE__)g,
      (__attribute__((address_space(3))) void*)l, 16, 0, 0);
}

// ---------------- fused fp32 -> bf16 convert (X, Wqkv, Wo in one launch) ----
__global__ __launch_bounds__(256) void cvt3_kernel(const float* __restrict__ a, u16* __restrict__ oa,
                                                   const float* __restrict__ b, u16* __restrict__ ob,
                                                   const float* __restrict__ c, u16* __restrict__ oc) {
  const float* in; u16* out; int off;
  int bid = blockIdx.x;
  if (bid < 4096)      { in = a; out = oa; off = bid; }
  else if (bid < 7168) { in = b; out = ob; off = bid - 4096; }
  else                 { in = c; out = oc; off = bid - 7168; }
  int i = (off * 256 + threadIdx.x) * 4;
  float4 v = *reinterpret_cast<const float4*>(in + i);
  u16x4 o = { f2bf(v.x), f2bf(v.y), f2bf(v.z), f2bf(v.w) };
  *reinterpret_cast<u16x4*>(out + i) = o;
}

// ---------------- GEMM: C[M,N] = A[M,K] * B[N,K]^T, 128x128 ---------------- (unchanged)
template<bool BF16OUT>
__global__ __launch_bounds__(256) void gemm_bt(const u16* __restrict__ A,
                                               const u16* __restrict__ B,
                                               void* __restrict__ Cv,
                                               int M, int N, int K) {
  __shared__ u16 At[128 * 64];
  __shared__ u16 Bt[128 * 64];
  const int tid  = threadIdx.x;
  const int wave = tid >> 6;
  const int lane = tid & 63;
  const int g    = lane >> 4;
  const int r16  = lane & 15;
  const int wr   = wave >> 1;
  const int wc   = wave & 1;
  const int bm   = blockIdx.y;
  const int bn   = blockIdx.x;

  const u16* Ab = A + (size_t)bm * 128 * K;
  const u16* Bb = B + (size_t)bn * 128 * K;
  const int srow = lane >> 3;
  const int scol = (lane & 7) * 8;

  f32x4 acc[4][4] = {};

  for (int kt = 0; kt < K; kt += 64) {
#pragma unroll
    for (int c = 0; c < 4; ++c) {
      int seg = wave * 4 + c;
      gld_lds16(Ab + (size_t)(seg * 8 + srow) * K + kt + scol, &At[seg * 512]);
      gld_lds16(Bb + (size_t)(seg * 8 + srow) * K + kt + scol, &Bt[seg * 512]);
    }
    __syncthreads();
#pragma unroll
    for (int ko = 0; ko < 64; ko += 32) {
      bf16x8 af[4], bfr[4];
#pragma unroll
      for (int mi = 0; mi < 4; ++mi)
        af[mi] = *reinterpret_cast<const bf16x8*>(&At[(wr * 64 + mi * 16 + r16) * 64 + ko + g * 8]);
#pragma unroll
      for (int ni = 0; ni < 4; ++ni)
        bfr[ni] = *reinterpret_cast<const bf16x8*>(&Bt[(wc * 64 + ni * 16 + r16) * 64 + ko + g * 8]);
#pragma unroll
      for (int mi = 0; mi < 4; ++mi)
#pragma unroll
        for (int ni = 0; ni < 4; ++ni)
          acc[mi][ni] = __builtin_amdgcn_mfma_f32_16x16x32_bf16(af[mi], bfr[ni], acc[mi][ni], 0, 0, 0);
    }
    __syncthreads();
  }

#pragma unroll
  for (int mi = 0; mi < 4; ++mi)
#pragma unroll
    for (int ni = 0; ni < 4; ++ni) {
      int row0 = bm * 128 + wr * 64 + mi * 16 + g * 4;
      int col  = bn * 128 + wc * 64 + ni * 16 + r16;
#pragma unroll
      for (int r = 0; r < 4; ++r) {
        float v = acc[mi][ni][r];
        if (BF16OUT) ((u16*)Cv)[(size_t)(row0 + r) * N + col] = f2bf(v);
        else         ((float*)Cv)[(size_t)(row0 + r) * N + col] = v;
      }
    }
}

// ---------------- GEMM: 128x64 tile (for O-proj: grid 512 = 2 blocks/CU) ----
// 4 waves stacked in M (wave w: rows w*32..w*32+31), each wave 32x64.
__global__ __launch_bounds__(256) void gemm_bt64(const u16* __restrict__ A,
                                                 const u16* __restrict__ B,
                                                 float* __restrict__ C,
                                                 int M, int N, int K) {
  __shared__ u16 At[128 * 64];
  __shared__ u16 Bt[64 * 64];
  const int tid  = threadIdx.x;
  const int wave = tid >> 6;
  const int lane = tid & 63;
  const int g    = lane >> 4;
  const int r16  = lane & 15;
  const int bm   = blockIdx.y;
  const int bn   = blockIdx.x;

  const u16* Ab = A + (size_t)bm * 128 * K;
  const u16* Bb = B + (size_t)bn * 64 * K;
  const int srow = lane >> 3;
  const int scol = (lane & 7) * 8;

  f32x4 acc[2][4] = {};

  for (int kt = 0; kt < K; kt += 64) {
#pragma unroll
    for (int c = 0; c < 4; ++c) {
      int seg = wave * 4 + c;
      gld_lds16(Ab + (size_t)(seg * 8 + srow) * K + kt + scol, &At[seg * 512]);
    }
#pragma unroll
    for (int c = 0; c < 2; ++c) {
      int seg = wave * 2 + c;
      gld_lds16(Bb + (size_t)(seg * 8 + srow) * K + kt + scol, &Bt[seg * 512]);
    }
    __syncthreads();
#pragma unroll
    for (int ko = 0; ko < 64; ko += 32) {
      bf16x8 af[2], bfr[4];
#pragma unroll
      for (int mi = 0; mi < 2; ++mi)
        af[mi] = *reinterpret_cast<const bf16x8*>(&At[(wave * 32 + mi * 16 + r16) * 64 + ko + g * 8]);
#pragma unroll
      for (int ni = 0; ni < 4; ++ni)
        bfr[ni] = *reinterpret_cast<const bf16x8*>(&Bt[(ni * 16 + r16) * 64 + ko + g * 8]);
#pragma unroll
      for (int mi = 0; mi < 2; ++mi)
#pragma unroll
        for (int ni = 0; ni < 4; ++ni)
          acc[mi][ni] = __builtin_amdgcn_mfma_f32_16x16x32_bf16(af[mi], bfr[ni], acc[mi][ni], 0, 0, 0);
    }
    __syncthreads();
  }

#pragma unroll
  for (int mi = 0; mi < 2; ++mi)
#pragma unroll
    for (int ni = 0; ni < 4; ++ni) {
      int row0 = bm * 128 + wave * 32 + mi * 16 + g * 4;
      int col  = bn * 64 + ni * 16 + r16;
#pragma unroll
      for (int r = 0; r < 4; ++r)
        C[(size_t)(row0 + r) * N + col] = acc[mi][ni][r];
    }
}

// ---------------- flash attention (R6 verbatim + setprio around MFMA) ----------------
__global__ __launch_bounds__(256, 4) void attn_kernel(const u16* __restrict__ qkv,
                                                      const float* __restrict__ mask,
                                                      u16* __restrict__ AO) {
  __shared__ u16 Kt[2][64 * 64];   // [key][d]   swizzled, double-buffered
  __shared__ u16 Vt[64 * 64];      // [d][key]   swizzled (transposed)
  __shared__ u16 Pl[4][16 * 64];   // per-wave P swizzled (wave-private)

  const int tid  = threadIdx.x;
  const int w    = tid >> 6;
  const int lane = tid & 63;
  const int g    = lane >> 4;
  const int r16  = lane & 15;

  const int n  = blockIdx.x;
  const int x  = n & 7;
  const int s_ = n >> 3;
  const int h  = s_ & 15;
  const int t_ = ((s_ >> 4) << 3) + x;
  const int b  = t_ >> 5;
  const int qt = t_ & 31;

  const size_t tokbase = (size_t)b * SEQ;

  bf16x8 aq[2];
  {
    int qrow = qt * 64 + w * 16 + r16;
#pragma unroll
    for (int ko = 0; ko < 2; ++ko)
      aq[ko] = *reinterpret_cast<const bf16x8*>(
          qkv + ((tokbase + qrow) * 3 + 0) * HID + h * HD + ko * 32 + g * 8);
  }

  f32x4 o[4] = {};
  float mrow[4], lrow[4];
#pragma unroll
  for (int r = 0; r < 4; ++r) { mrow[r] = -3.0e38f; lrow[r] = 0.f; }

  const int srowK = lane >> 3;        // 0..7
  const int vkey  = tid >> 2;         // 0..63
  const int vd3   = tid & 3;

#define STAGE_K(buf, kb)                                                        \
  {                                                                             \
    _Pragma("unroll")                                                           \
    for (int c = 0; c < 2; ++c) {                                               \
      int seg = w * 2 + c;                                                      \
      int sK  = ((seg >> 1) + srowK) & 7;                                       \
      int srcc = (lane & 7) ^ sK;                                               \
      gld_lds16(qkv + ((tokbase + (kb) + seg * 8 + srowK) * 3 + 1) * HID +      \
                    h * HD + srcc * 8,                                          \
                &Kt[buf][seg * 512]);                                           \
    }                                                                           \
  }

  // ---- prologue: K tile 0 in flight ----
  STAGE_K(0, 0);

#pragma unroll 1
  for (int kb = 0; kb < SEQ; kb += 64) {
    const int cur = (kb >> 6) & 1;
    const int nxt = cur ^ 1;
    const bool more = (kb + 64) < SEQ;

    // ---- reg loads for THIS tile: mask + V ----
    float mpre[4][4];
#pragma unroll
    for (int r = 0; r < 4; ++r) {
      int q = qt * 64 + w * 16 + g * 4 + r;
      const float* mp = mask + ((size_t)b * SEQ + q) * SEQ + kb;
#pragma unroll
      for (int ni = 0; ni < 4; ++ni) mpre[r][ni] = mp[ni * 16 + r16];
    }
    const u16* vp = qkv + ((tokbase + kb + vkey) * 3 + 2) * HID + h * HD + vd3 * 16;
    u16x8 v0 = *reinterpret_cast<const u16x8*>(vp);
    u16x8 v1 = *reinterpret_cast<const u16x8*>(vp + 8);

    __syncthreads();   // A: prev-tile LDS reads done; drains vmcnt

    // ---- V -> LDS transposed, swizzled scalar writes ----
#pragma unroll
    for (int j = 0; j < 16; ++j) {
      u16 val = (j < 8) ? (u16)v0[j] : (u16)v1[j - 8];
      int row = vd3 * 16 + j;
      int sV  = (vd3 + (j & 7)) & 7;
      Vt[row * 64 + (((vkey >> 3) ^ sV) << 3) + (vkey & 7)] = val;
    }
    __syncthreads();   // B: Vt + Kt[cur] visible to all waves

    // ---- S = Q K^T on Kt[cur] ----
    f32x4 sf[4] = {};
    __builtin_amdgcn_s_setprio(1);
#pragma unroll
    for (int ko = 0; ko < 2; ++ko) {
      bf16x8 bk[4];
#pragma unroll
      for (int ni = 0; ni < 4; ++ni) {
        int row = ni * 16 + r16;
        int sK  = (ni + (r16 & 7)) & 7;
        bk[ni] = *reinterpret_cast<const bf16x8*>(
            &Kt[cur][row * 64 + (((ko * 4 + g) ^ sK) << 3)]);
      }
#pragma unroll
      for (int ni = 0; ni < 4; ++ni)
        sf[ni] = __builtin_amdgcn_mfma_f32_16x16x32_bf16(aq[ko], bk[ni], sf[ni], 0, 0, 0);
    }
    __builtin_amdgcn_s_setprio(0);

    // ---- online softmax (rows at g*4+r, cols at r16) ----
#pragma unroll
    for (int r = 0; r < 4; ++r) {
      float mx = -3.0e38f;
#pragma unroll
      for (int ni = 0; ni < 4; ++ni) {
        float sv = sf[ni][r] * 0.125f + mpre[r][ni];
        sf[ni][r] = sv;
        mx = fmaxf(mx, sv);
      }
      mx = fmaxf(mx, __shfl_xor(mx, 1));
      mx = fmaxf(mx, __shfl_xor(mx, 2));
      mx = fmaxf(mx, __shfl_xor(mx, 4));
      mx = fmaxf(mx, __shfl_xor(mx, 8));
      float mnew  = fmaxf(mrow[r], mx);
      float alpha = __expf(mrow[r] - mnew);
      mrow[r] = mnew;
      float s = 0.f;
#pragma unroll
      for (int ni = 0; ni < 4; ++ni) {
        float p = __expf(sf[ni][r] - mnew);
        sf[ni][r] = p;
        s += p;
      }
      s += __shfl_xor(s, 1); s += __shfl_xor(s, 2);
      s += __shfl_xor(s, 4); s += __shfl_xor(s, 8);
      lrow[r] = lrow[r] * alpha + s;
#pragma unroll
      for (int di = 0; di < 4; ++di) o[di][r] *= alpha;
      int prow = g * 4 + r;
      int sP   = prow & 7;
#pragma unroll
      for (int ni = 0; ni < 4; ++ni) {
        int chunk = ni * 2 + (r16 >> 3);
        Pl[w][prow * 64 + ((chunk ^ sP) << 3) + (r16 & 7)] = f2bf(sf[ni][r]);
      }
    }
    // no barrier: Pl[w] is wave-private; lgkmcnt orders write->read

    // ---- prefetch next K tile (zero-register) ----
    if (more) STAGE_K(nxt, kb + 64);

    // ---- O += P V ----
    __builtin_amdgcn_s_setprio(1);
#pragma unroll
    for (int kk = 0; kk < 2; ++kk) {
      bf16x8 pa, bv[4];
      pa = *reinterpret_cast<const bf16x8*>(
          &Pl[w][r16 * 64 + (((kk * 4 + g) ^ (r16 & 7)) << 3)]);
#pragma unroll
      for (int di = 0; di < 4; ++di) {
        int row = di * 16 + r16;
        int sV  = (di + (r16 & 7)) & 7;
        bv[di] = *reinterpret_cast<const bf16x8*>(
            &Vt[row * 64 + (((kk * 4 + g) ^ sV) << 3)]);
      }
#pragma unroll
      for (int di = 0; di < 4; ++di)
        o[di] = __builtin_amdgcn_mfma_f32_16x16x32_bf16(pa, bv[di], o[di], 0, 0, 0);
    }
    __builtin_amdgcn_s_setprio(0);
  }

  // finalize
#pragma unroll
  for (int di = 0; di < 4; ++di)
#pragma unroll
    for (int r = 0; r < 4; ++r) {
      int srow = qt * 64 + w * 16 + g * 4 + r;
      float val = o[di][r] / lrow[r];
      AO[(tokbase + srow) * HID + h * HD + di * 16 + r16] = f2bf(val);
    }
#undef STAGE_K
}

// ---------------- launcher ----------------
extern "C" void kernel_launch(void* const* d_in, const int* in_sizes, int n_in,
                              void* d_out, int out_size, void* d_ws, size_t ws_size,
                              hipStream_t stream) {
  (void)in_sizes; (void)n_in; (void)out_size; (void)ws_size;
  const float* hs   = (const float*)d_in[0];
  const float* mask = (const float*)d_in[1];
  const float* wqkv = (const float*)d_in[2];
  const float* wo   = (const float*)d_in[3];
  float* out = (float*)d_out;

  char* ws   = (char*)d_ws;
  u16* Xb    = (u16*)(ws);                        // 4096x1024  (8 MiB)
  u16* Wqkvb = (u16*)(ws + 8u  * 1024 * 1024);    // 3072x1024  (6 MiB)
  u16* Wob   = (u16*)(ws + 14u * 1024 * 1024);    // 1024x1024  (2 MiB)
  u16* QKVb  = (u16*)(ws + 16u * 1024 * 1024);    // 4096x3072  (24 MiB)
  u16* AOb   = (u16*)(ws + 40u * 1024 * 1024);    // 4096x1024  (8 MiB)

  cvt3_kernel<<<8192, 256, 0, stream>>>(hs, Xb, wqkv, Wqkvb, wo, Wob);

  gemm_bt<true><<<dim3(3072 / 128, 4096 / 128), 256, 0, stream>>>(Xb, Wqkvb, QKVb, NTOK, 3072, HID);
  attn_kernel  <<<1024, 256, 0, stream>>>(QKVb, mask, AOb);
  gemm_bt64    <<<dim3(1024 / 64, 4096 / 128), 256, 0, stream>>>(AOb, Wob, out, NTOK, 1024, HID);
}